// Round 1
// baseline (337.864 us; speedup 1.0000x reference)
//
#include <hip/hip_runtime.h>
#include <hip/hip_bf16.h>

// (B,N,T,F) = (16,512,24,64). FP32 in/out.
#define BB 16
#define NN 512
#define TT 24
#define FF 64
#define OUT_OFF ((size_t)BB*NN*TT*FF)   // 12582912 floats (of | uf concatenated)

#define AIS 136      // Aj row stride, shorts (272B = 17*16B, odd 16B units)
#define XTS 72       // Xt/Ut/O/W row stride (144B = 9*16B, odd)
#define XTSZ 4672    // per-matrix region (64*72 + swizzle slack)

typedef __attribute__((ext_vector_type(8))) short v8s;
typedef __attribute__((ext_vector_type(4))) float v4f;

union U16x8 { uint4 v; unsigned short s[8]; };

__device__ inline v4f mfma16(v8s a, v8s b, v4f c) {
    return __builtin_amdgcn_mfma_f32_16x16x32_bf16(a, b, c, 0, 0, 0);
}

// ---- cheap bf16 conversion machinery (no NaN path; inputs are finite) ----
__device__ inline unsigned int fbits(float x) {
    union { float f; unsigned int u; } c; c.f = x; return c.u;
}
__device__ inline float ibits(unsigned int u) {
    union { float f; unsigned int u; } c; c.u = u; return c.f;
}
// round-half-up bf16: <=0.5 ulp error, 2 VALU ops
__device__ inline unsigned short f2bf_r(float x) {
    return (unsigned short)((fbits(x) + 0x8000u) >> 16);
}
__device__ inline float bf2f(unsigned short u) {
    return ibits(((unsigned int)u) << 16);
}
// hi/lo split: hi = round-half-up bf16, lo = bf16(f - hi) (exact residual)
__device__ inline void split8(const float* f, U16x8& H, U16x8& L) {
    #pragma unroll
    for (int k = 0; k < 8; ++k) {
        unsigned int u  = fbits(f[k]);
        unsigned int hr = (u + 0x8000u) & 0xffff0000u;
        H.s[k] = (unsigned short)(hr >> 16);
        float lo = f[k] - ibits(hr);
        L.s[k] = (unsigned short)((fbits(lo) + 0x8000u) >> 16);
    }
}
// hi-only convert of 8 elements
__device__ inline void cvt8h(const float* f, U16x8& H) {
    #pragma unroll
    for (int k = 0; k < 8; ++k) H.s[k] = f2bf_r(f[k]);
}

__global__ __launch_bounds__(256, 3)
void spag_kernel(const float* __restrict__ ori, const float* __restrict__ unc,
                 const float* __restrict__ emb, const float* __restrict__ W1,
                 float* __restrict__ out)
{
    // One 53504B arena, 3 blocks/CU (160 KiB LDS). Regions:
    //   AjH[64*AIS] | AjL[64*AIS] | XT[XTSZ] | UT[XTSZ]
    // Prologue aliases AjH/AjL as Ai hi/lo staging; epilogue aliases
    // XT/UT as Ox/Ou and AjH as the W1 tile.
    __shared__ __align__(16) unsigned short SH[2*64*AIS + 2*XTSZ];
    unsigned short* AjH = SH;
    unsigned short* AjL = SH + 64*AIS;
    unsigned short* XT  = SH + 2*64*AIS;
    unsigned short* UT  = XT + XTSZ;

    const int tid  = threadIdx.x;
    const int bt   = blockIdx.x >> 3;      // 0..383
    const int it   = blockIdx.x & 7;
    const int b    = bt / TT, t = bt % TT;
    const int i0   = it * 64;

    const int lane = tid & 63;
    const int w    = tid >> 6;             // wave -> i rows w*16..w*16+15
    const int q    = lane >> 4;            // quad
    const int lc   = lane & 15;

    // ---- prologue: stage Ai hi/lo (into AjH/AjL regions), load B-frags ----
    {
        const int sr = tid >> 2, fc = (tid & 3) * 16;
        const float* xb = ori + ((size_t)((b*NN + i0 + sr)*TT + t))*FF + fc;
        const float* eb = emb + (size_t)(i0 + sr)*FF + fc;
        float tf[8]; U16x8 H, L;
        #pragma unroll
        for (int h = 0; h < 2; ++h) {
            *(float4*)&tf[0] = ((const float4*)xb)[2*h];
            *(float4*)&tf[4] = ((const float4*)xb)[2*h+1];
            split8(tf, H, L);
            *(uint4*)&AjH[sr*AIS + fc + h*8] = H.v;
            *(uint4*)&AjL[sr*AIS + fc + h*8] = L.v;
            *(float4*)&tf[0] = ((const float4*)eb)[2*h];
            *(float4*)&tf[4] = ((const float4*)eb)[2*h+1];
            split8(tf, H, L);
            *(uint4*)&AjH[sr*AIS + 64 + fc + h*8] = H.v;
            *(uint4*)&AjL[sr*AIS + 64 + fc + h*8] = L.v;
        }
    }
    __syncthreads();

    v8s bH[4], bL[4];   // i-side fragments, register-resident all kernel
    #pragma unroll
    for (int kk = 0; kk < 4; ++kk) {
        bH[kk] = *(const v8s*)&AjH[(w*16+lc)*AIS + kk*32 + q*8];
        bL[kk] = *(const v8s*)&AjL[(w*16+lc)*AIS + kk*32 + q*8];
    }

    v4f accX[4], accU[4];
    #pragma unroll
    for (int ft = 0; ft < 4; ++ft) { accX[ft] = (v4f)(0.0f); accU[ft] = (v4f)(0.0f); }
    float rs    = 0.0f;   // softmax denom partial for row i = w*16+lc (at m_run)
    float m_run = 0.0f;   // running row max of relu'd scores (>= 0)

    for (int jt = 0; jt < 8; ++jt) {
        const int j0 = jt * 64;
        __syncthreads();   // prev iter's LDS readers done (and prologue frag reads, jt=0)

        // ---- single-pass staging: AjH, AjL, XT, UT ----
        {
            const int pj = tid >> 3;           // j pair (2pj, 2pj+1)
            const int f0 = (tid & 7) * 8;      // f chunk
            const int j  = 2 * pj;
            const size_t r0 = ((size_t)((b*NN + j0 + j)*TT + t))*FF + f0;
            const size_t r1 = r0 + (size_t)TT*FF;
            float t0[8], t1[8]; U16x8 H0, L0, H1, L1;

            // ori: hi->AjH, lo->AjL, hi also transposed -> XT
            *(float4*)&t0[0] = *(const float4*)(ori + r0);
            *(float4*)&t0[4] = *(const float4*)(ori + r0 + 4);
            *(float4*)&t1[0] = *(const float4*)(ori + r1);
            *(float4*)&t1[4] = *(const float4*)(ori + r1 + 4);
            split8(t0, H0, L0); split8(t1, H1, L1);
            *(uint4*)&AjH[ j   *AIS + f0] = H0.v;
            *(uint4*)&AjH[(j+1)*AIS + f0] = H1.v;
            *(uint4*)&AjL[ j   *AIS + f0] = L0.v;
            *(uint4*)&AjL[(j+1)*AIS + f0] = L1.v;
            #pragma unroll
            for (int k = 0; k < 8; ++k) {
                int f = f0 + k;
                int off = f*XTS + (f>>4)*16 + j;
                *(unsigned int*)&XT[off] =
                    (unsigned int)H0.s[k] | ((unsigned int)H1.s[k] << 16);
            }
            // emb: hi->AjH(+64), lo->AjL(+64)
            const float* e0 = emb + (size_t)(j0 + j)*FF + f0;
            *(float4*)&t0[0] = *(const float4*)(e0);
            *(float4*)&t0[4] = *(const float4*)(e0 + 4);
            *(float4*)&t1[0] = *(const float4*)(e0 + FF);
            *(float4*)&t1[4] = *(const float4*)(e0 + FF + 4);
            split8(t0, H0, L0); split8(t1, H1, L1);
            *(uint4*)&AjH[ j   *AIS + 64 + f0] = H0.v;
            *(uint4*)&AjH[(j+1)*AIS + 64 + f0] = H1.v;
            *(uint4*)&AjL[ j   *AIS + 64 + f0] = L0.v;
            *(uint4*)&AjL[(j+1)*AIS + 64 + f0] = L1.v;
            // unc: hi only, transposed -> UT
            *(float4*)&t0[0] = *(const float4*)(unc + r0);
            *(float4*)&t0[4] = *(const float4*)(unc + r0 + 4);
            *(float4*)&t1[0] = *(const float4*)(unc + r1);
            *(float4*)&t1[4] = *(const float4*)(unc + r1 + 4);
            #pragma unroll
            for (int k = 0; k < 8; ++k) {
                int f = f0 + k;
                int off = f*XTS + (f>>4)*16 + j;
                *(unsigned int*)&UT[off] =
                    (unsigned int)f2bf_r(t0[k]) | ((unsigned int)f2bf_r(t1[k]) << 16);
            }
        }
        __syncthreads();

        // ---- scores: C(S^T)[j][i] = Aj . Ai^T, hi/lo split (48 MFMA) ----
        v4f C[4] = {(v4f)(0.0f),(v4f)(0.0f),(v4f)(0.0f),(v4f)(0.0f)};
        #pragma unroll
        for (int kk = 0; kk < 4; ++kk) {
            #pragma unroll
            for (int st = 0; st < 4; ++st) {
                v8s aH = *(const v8s*)&AjH[(st*16+lc)*AIS + kk*32 + q*8];
                v8s aL = *(const v8s*)&AjL[(st*16+lc)*AIS + kk*32 + q*8];
                C[st] = mfma16(aH, bH[kk], C[st]);
                C[st] = mfma16(aH, bL[kk], C[st]);
                C[st] = mfma16(aL, bH[kk], C[st]);
            }
        }

        // ---- online softmax: relu, tile row-max, rescale, p = exp(s - m) ----
        float mt = 0.0f;
        #pragma unroll
        for (int st = 0; st < 4; ++st) {
            #pragma unroll
            for (int r = 0; r < 4; ++r) {
                float s = fmaxf(C[st][r], 0.0f);
                C[st][r] = s;
                mt = fmaxf(mt, s);
            }
        }
        mt = fmaxf(mt, __shfl_xor(mt, 16));
        mt = fmaxf(mt, __shfl_xor(mt, 32));
        float m_new = fmaxf(m_run, mt);
        float alpha = __expf(m_run - m_new);
        rs *= alpha;
        m_run = m_new;
        float alphar[4];
        #pragma unroll
        for (int r = 0; r < 4; ++r) alphar[r] = __shfl(alpha, q*4 + r);
        #pragma unroll
        for (int ft = 0; ft < 4; ++ft) {
            #pragma unroll
            for (int r = 0; r < 4; ++r) { accX[ft][r] *= alphar[r]; accU[ft][r] *= alphar[r]; }
        }
        #pragma unroll
        for (int st = 0; st < 4; ++st) {
            #pragma unroll
            for (int r = 0; r < 4; ++r) C[st][r] = __expf(C[st][r] - m_new);
        }

        // ---- repack p: C-layout -> A-layout (in-wave shfl), accumulate rowsum ----
        v8s P[2];
        #pragma unroll
        for (int kk = 0; kk < 2; ++kk) {
            union { v8s v; unsigned short s[8]; } pf;
            #pragma unroll
            for (int jj = 0; jj < 8; ++jj) {
                int src = ((q & 1)*2 + (jj >> 2))*16 + lc;
                float v0 = __shfl(C[2*kk + 0][jj & 3], src);
                float v1 = __shfl(C[2*kk + 1][jj & 3], src);
                float pv = (q >> 1) ? v1 : v0;
                unsigned short pb = f2bf_r(pv);
                pf.s[jj] = pb;
                rs += bf2f(pb);
            }
            P[kk] = pf.v;
        }

        // ---- PV: accX += P . x^T, accU += P . u^T (16 MFMA) ----
        #pragma unroll
        for (int ft = 0; ft < 4; ++ft) {
            #pragma unroll
            for (int kk = 0; kk < 2; ++kk) {
                v8s bx = *(const v8s*)&XT[(ft*16+lc)*XTS + ft*16 + kk*32 + q*8];
                v8s bu = *(const v8s*)&UT[(ft*16+lc)*XTS + ft*16 + kk*32 + q*8];
                accX[ft] = mfma16(P[kk], bx, accX[ft]);
                accU[ft] = mfma16(P[kk], bu, accU[ft]);
            }
        }
    }

    // ---- epilogue: normalize, O.W1^T, relu, fp32 stores ----
    __syncthreads();                           // all PV reads done
    rs += __shfl_xor(rs, 16);
    rs += __shfl_xor(rs, 32);                  // full row sum (>= 1)
    float inv = 1.0f / rs;
    float invr[4];
    #pragma unroll
    for (int r = 0; r < 4; ++r) invr[r] = __shfl(inv, q*4 + r);

    unsigned short* Ox = XT;
    unsigned short* Ou = UT;
    #pragma unroll
    for (int ft = 0; ft < 4; ++ft) {
        #pragma unroll
        for (int r = 0; r < 4; ++r) {
            int row = w*16 + q*4 + r;
            Ox[row*XTS + ft*16 + lc] = f2bf_r(accX[ft][r] * invr[r]);
            Ou[row*XTS + ft*16 + lc] = f2bf_r(accU[ft][r] * invr[r]);
        }
    }
    // W1 tile -> AjH region (stride XTS)
    {
        const int sr = tid >> 2, fc = (tid & 3) * 16;
        const float* wb = W1 + sr*FF + fc;
        float tf[8]; U16x8 H;
        #pragma unroll
        for (int h = 0; h < 2; ++h) {
            *(float4*)&tf[0] = ((const float4*)wb)[2*h];
            *(float4*)&tf[4] = ((const float4*)wb)[2*h+1];
            cvt8h(tf, H);
            *(uint4*)&AjH[sr*XTS + fc + h*8] = H.v;
        }
    }
    __syncthreads();

    #pragma unroll
    for (int ot = 0; ot < 4; ++ot) {
        v4f ax = (v4f)(0.0f), au = (v4f)(0.0f);
        #pragma unroll
        for (int kk = 0; kk < 2; ++kk) {
            v8s aox = *(const v8s*)&Ox[(w*16+lc)*XTS + kk*32 + q*8];
            v8s aou = *(const v8s*)&Ou[(w*16+lc)*XTS + kk*32 + q*8];
            v8s bw  = *(const v8s*)&AjH[(ot*16+lc)*XTS + kk*32 + q*8];
            ax = mfma16(aox, bw, ax);
            au = mfma16(aou, bw, au);
        }
        #pragma unroll
        for (int r = 0; r < 4; ++r) {
            int i = i0 + w*16 + q*4 + r;
            int o = ot*16 + lc;
            size_t idx = ((size_t)((b*NN + i)*TT + t))*FF + o;
            out[idx]           = fmaxf(ax[r], 0.0f);
            out[OUT_OFF + idx] = fmaxf(au[r], 0.0f);
        }
    }
}

extern "C" void kernel_launch(void* const* d_in, const int* in_sizes, int n_in,
                              void* d_out, int out_size, void* d_ws, size_t ws_size,
                              hipStream_t stream) {
    const float* ori = (const float*)d_in[0];
    const float* unc = (const float*)d_in[1];
    const float* emb = (const float*)d_in[2];
    const float* W1  = (const float*)d_in[3];
    float* out = (float*)d_out;

    spag_kernel<<<dim3(BB*TT*8), dim3(256), 0, stream>>>(ori, unc, emb, W1, out);
}

// Round 2
// 268.235 us; speedup vs baseline: 1.2596x; 1.2596x over previous
//
#include <hip/hip_runtime.h>
#include <hip/hip_bf16.h>

// (B,N,T,F) = (16,512,24,64). FP32 in/out.
#define BB 16
#define NN 512
#define TT 24
#define FF 64
#define OUT_OFF ((size_t)BB*NN*TT*FF)   // 12582912 floats (of | uf concatenated)

#define AIS 136      // Aj row stride, shorts (272B = 17*16B, odd 16B units)
#define XTS 72       // Xt/Ut/O/W row stride (144B = 9*16B, odd)
#define XTSZ 4672    // per-matrix region (64*72 + swizzle slack)

typedef __attribute__((ext_vector_type(8))) short v8s;
typedef __attribute__((ext_vector_type(16))) float v16f;

union U16x8 { uint4 v; unsigned short s[8]; };

__device__ inline v16f mfma32(v8s a, v8s b, v16f c) {
    return __builtin_amdgcn_mfma_f32_32x32x16_bf16(a, b, c, 0, 0, 0);
}

// ---- cheap bf16 conversion machinery (no NaN path; inputs are finite) ----
__device__ inline unsigned int fbits(float x) {
    union { float f; unsigned int u; } c; c.f = x; return c.u;
}
__device__ inline float ibits(unsigned int u) {
    union { float f; unsigned int u; } c; c.u = u; return c.f;
}
__device__ inline unsigned short f2bf_r(float x) {
    return (unsigned short)((fbits(x) + 0x8000u) >> 16);
}
__device__ inline float bf2f(unsigned short u) {
    return ibits(((unsigned int)u) << 16);
}
__device__ inline void split8(const float* f, U16x8& H, U16x8& L) {
    #pragma unroll
    for (int k = 0; k < 8; ++k) {
        unsigned int u  = fbits(f[k]);
        unsigned int hr = (u + 0x8000u) & 0xffff0000u;
        H.s[k] = (unsigned short)(hr >> 16);
        float lo = f[k] - ibits(hr);
        L.s[k] = (unsigned short)((fbits(lo) + 0x8000u) >> 16);
    }
}
__device__ inline void cvt8h(const float* f, U16x8& H) {
    #pragma unroll
    for (int k = 0; k < 8; ++k) H.s[k] = f2bf_r(f[k]);
}

// pack two f32 (already bf16-representable) into one dword of 2 bf16 (exact)
__device__ inline unsigned int pkbf(float a, float b) {
    unsigned int r;
    asm("v_cvt_pk_bf16_f32 %0, %1, %2" : "=v"(r) : "v"(a), "v"(b));
    return r;
}

// Build one 32x32x16 A-fragment (K=16 chunk, c=0 -> j' 0..15, c=1 -> j' 16..31)
// from the C-layout softmax values cr[16] of one 32x32 score tile.
// C-layout: lane (m=l&31, hi=l>>5) holds j' = (r&3)+8*(r>>2)+4*hi at reg r.
// A-layout: lane holds row i=m, k = hi*8 + e.
// Derivation: e0..3 / e4..7 come from regs 8c+g / 8c+4+g of own/partner lane;
// one v_permlane32_swap_b32 per dword pair does the half-wave exchange.
__device__ inline v8s pfrag(const float* cr, int c) {
    unsigned int a0 = pkbf(cr[8*c+0], cr[8*c+1]);
    unsigned int a1 = pkbf(cr[8*c+2], cr[8*c+3]);
    unsigned int b0 = pkbf(cr[8*c+4], cr[8*c+5]);
    unsigned int b1 = pkbf(cr[8*c+6], cr[8*c+7]);
    // after: aX' = {aX.lo32 | bX.lo32 moved up}, bX' = {aX.hi32 | bX.hi32}
    asm("v_permlane32_swap_b32 %0, %1" : "+v"(a0), "+v"(b0));
    asm("v_permlane32_swap_b32 %0, %1" : "+v"(a1), "+v"(b1));
    union { v8s v; unsigned int u[4]; } P;
    P.u[0] = a0; P.u[1] = a1; P.u[2] = b0; P.u[3] = b1;
    return P.v;
}

__global__ __launch_bounds__(256, 2)
void spag_kernel(const float* __restrict__ ori, const float* __restrict__ unc,
                 const float* __restrict__ emb, const float* __restrict__ W1,
                 float* __restrict__ out)
{
    // One 53504B arena, 2 blocks/CU. Regions (main loop):
    //   AjH[64*AIS] | AjL[64*AIS] | XT[XTSZ] | UT[XTSZ]
    // Prologue aliases AjH/AjL as Ai hi/lo staging (2 passes of 64 rows).
    // Epilogue re-carves the arena as Ox[128*XTS] | Ou[128*XTS] | Wt[64*XTS].
    __shared__ __align__(16) unsigned short SH[2*64*AIS + 2*XTSZ];
    unsigned short* AjH = SH;
    unsigned short* AjL = SH + 64*AIS;
    unsigned short* XT  = SH + 2*64*AIS;
    unsigned short* UT  = XT + XTSZ;

    const int tid  = threadIdx.x;
    const int bt   = blockIdx.x >> 2;      // 0..383
    const int it   = blockIdx.x & 3;
    const int b    = bt / TT, t = bt % TT;
    const int i0   = it * 128;

    const int lane = tid & 63;
    const int w    = tid >> 6;             // wave -> i rows w*32..w*32+31
    const int m    = lane & 31;
    const int hi   = lane >> 5;

    // ---- prologue: stage Ai hi/lo in 2 passes of 64 rows, grab B-frags ----
    v8s bH[8], bL[8];   // i-side fragments, register-resident all kernel
    #pragma unroll
    for (int p = 0; p < 2; ++p) {
        {
            const int sr = tid >> 2, fc = (tid & 3) * 16;
            const float* xb = ori + ((size_t)((b*NN + i0 + p*64 + sr)*TT + t))*FF + fc;
            const float* eb = emb + (size_t)(i0 + p*64 + sr)*FF + fc;
            float tf[8]; U16x8 H, L;
            #pragma unroll
            for (int h = 0; h < 2; ++h) {
                *(float4*)&tf[0] = ((const float4*)xb)[2*h];
                *(float4*)&tf[4] = ((const float4*)xb)[2*h+1];
                split8(tf, H, L);
                *(uint4*)&AjH[sr*AIS + fc + h*8] = H.v;
                *(uint4*)&AjL[sr*AIS + fc + h*8] = L.v;
                *(float4*)&tf[0] = ((const float4*)eb)[2*h];
                *(float4*)&tf[4] = ((const float4*)eb)[2*h+1];
                split8(tf, H, L);
                *(uint4*)&AjH[sr*AIS + 64 + fc + h*8] = H.v;
                *(uint4*)&AjL[sr*AIS + 64 + fc + h*8] = L.v;
            }
        }
        __syncthreads();
        if ((w >> 1) == p) {
            const int lr = (w & 1)*32 + m;
            #pragma unroll
            for (int kk = 0; kk < 8; ++kk) {
                bH[kk] = *(const v8s*)&AjH[lr*AIS + kk*16 + hi*8];
                bL[kk] = *(const v8s*)&AjL[lr*AIS + kk*16 + hi*8];
            }
        }
        __syncthreads();
    }

    v16f accX0 = (v16f)(0.0f), accX1 = (v16f)(0.0f);
    v16f accU0 = (v16f)(0.0f), accU1 = (v16f)(0.0f);
    float rs    = 0.0f;   // softmax denom partial for row i = lane&31 (at m_run)
    float m_run = 0.0f;   // running row max of relu'd scores (>= 0)

    for (int jt = 0; jt < 8; ++jt) {
        const int j0 = jt * 64;
        __syncthreads();   // prev iter's LDS readers done

        // ---- single-pass staging: AjH, AjL, XT, UT (unchanged) ----
        {
            const int pj = tid >> 3;           // j pair (2pj, 2pj+1)
            const int f0 = (tid & 7) * 8;      // f chunk
            const int j  = 2 * pj;
            const size_t r0 = ((size_t)((b*NN + j0 + j)*TT + t))*FF + f0;
            const size_t r1 = r0 + (size_t)TT*FF;
            float t0[8], t1[8]; U16x8 H0, L0, H1, L1;

            // ori: hi->AjH, lo->AjL, hi also transposed -> XT
            *(float4*)&t0[0] = *(const float4*)(ori + r0);
            *(float4*)&t0[4] = *(const float4*)(ori + r0 + 4);
            *(float4*)&t1[0] = *(const float4*)(ori + r1);
            *(float4*)&t1[4] = *(const float4*)(ori + r1 + 4);
            split8(t0, H0, L0); split8(t1, H1, L1);
            *(uint4*)&AjH[ j   *AIS + f0] = H0.v;
            *(uint4*)&AjH[(j+1)*AIS + f0] = H1.v;
            *(uint4*)&AjL[ j   *AIS + f0] = L0.v;
            *(uint4*)&AjL[(j+1)*AIS + f0] = L1.v;
            #pragma unroll
            for (int k = 0; k < 8; ++k) {
                int f = f0 + k;
                int off = f*XTS + (f>>4)*16 + j;
                *(unsigned int*)&XT[off] =
                    (unsigned int)H0.s[k] | ((unsigned int)H1.s[k] << 16);
            }
            // emb: hi->AjH(+64), lo->AjL(+64)
            const float* e0 = emb + (size_t)(j0 + j)*FF + f0;
            *(float4*)&t0[0] = *(const float4*)(e0);
            *(float4*)&t0[4] = *(const float4*)(e0 + 4);
            *(float4*)&t1[0] = *(const float4*)(e0 + FF);
            *(float4*)&t1[4] = *(const float4*)(e0 + FF + 4);
            split8(t0, H0, L0); split8(t1, H1, L1);
            *(uint4*)&AjH[ j   *AIS + 64 + f0] = H0.v;
            *(uint4*)&AjH[(j+1)*AIS + 64 + f0] = H1.v;
            *(uint4*)&AjL[ j   *AIS + 64 + f0] = L0.v;
            *(uint4*)&AjL[(j+1)*AIS + 64 + f0] = L1.v;
            // unc: hi only, transposed -> UT
            *(float4*)&t0[0] = *(const float4*)(unc + r0);
            *(float4*)&t0[4] = *(const float4*)(unc + r0 + 4);
            *(float4*)&t1[0] = *(const float4*)(unc + r1);
            *(float4*)&t1[4] = *(const float4*)(unc + r1 + 4);
            #pragma unroll
            for (int k = 0; k < 8; ++k) {
                int f = f0 + k;
                int off = f*XTS + (f>>4)*16 + j;
                *(unsigned int*)&UT[off] =
                    (unsigned int)f2bf_r(t0[k]) | ((unsigned int)f2bf_r(t1[k]) << 16);
            }
        }
        __syncthreads();

        // ---- scores: C_tau(S^T)[j][i], 32x32 tiles, hi/lo split (48 MFMA) ----
        v16f C0 = (v16f)(0.0f), C1 = (v16f)(0.0f);
        #pragma unroll
        for (int kk = 0; kk < 8; ++kk) {
            const int fo = kk*16 + hi*8;
            v8s aH0 = *(const v8s*)&AjH[ m     *AIS + fo];
            v8s aL0 = *(const v8s*)&AjL[ m     *AIS + fo];
            v8s aH1 = *(const v8s*)&AjH[(32+m)*AIS + fo];
            v8s aL1 = *(const v8s*)&AjL[(32+m)*AIS + fo];
            C0 = mfma32(aH0, bH[kk], C0);
            C1 = mfma32(aH1, bH[kk], C1);
            C0 = mfma32(aH0, bL[kk], C0);
            C1 = mfma32(aH1, bL[kk], C1);
            C0 = mfma32(aL0, bH[kk], C0);
            C1 = mfma32(aL1, bH[kk], C1);
        }

        // ---- online softmax with defer-max (T13, THR=8) ----
        float mt = 0.0f;
        #pragma unroll
        for (int r = 0; r < 16; ++r) {
            float s0 = fmaxf(C0[r], 0.0f); C0[r] = s0;
            float s1 = fmaxf(C1[r], 0.0f); C1[r] = s1;
            mt = fmaxf(mt, fmaxf(s0, s1));
        }
        mt = fmaxf(mt, __shfl_xor(mt, 32));
        if (!__all(mt <= m_run + 8.0f)) {
            float m_new = fmaxf(m_run, mt);
            float al = __expf(m_run - m_new);
            rs *= al; m_run = m_new;
            #pragma unroll
            for (int r = 0; r < 16; ++r) {
                float a = __shfl(al, (r & 3) + 8*(r >> 2) + 4*hi);
                accX0[r] *= a; accX1[r] *= a;
                accU0[r] *= a; accU1[r] *= a;
            }
        }

        // ---- p = exp(s - m_run), round to bf16, rowsum, repack to A-frags ----
        v8s P[4];
        {
            float cr[16];
            #pragma unroll
            for (int r = 0; r < 16; ++r) {
                float e = __expf(C0[r] - m_run);
                cr[r] = ibits((fbits(e) + 0x8000u) & 0xffff0000u);
                rs += cr[r];
            }
            P[0] = pfrag(cr, 0);
            P[1] = pfrag(cr, 1);
            #pragma unroll
            for (int r = 0; r < 16; ++r) {
                float e = __expf(C1[r] - m_run);
                cr[r] = ibits((fbits(e) + 0x8000u) & 0xffff0000u);
                rs += cr[r];
            }
            P[2] = pfrag(cr, 0);
            P[3] = pfrag(cr, 1);
        }

        // ---- PV: accX += P . x^T, accU += P . u^T (16 MFMA) ----
        #pragma unroll
        for (int kk = 0; kk < 4; ++kk) {
            const int fo = kk*16 + hi*8;
            v8s bx0 = *(const v8s*)&XT[ m     *XTS + (( m    )>>4)*16 + fo];
            v8s bu0 = *(const v8s*)&UT[ m     *XTS + (( m    )>>4)*16 + fo];
            v8s bx1 = *(const v8s*)&XT[(32+m)*XTS + (((32+m))>>4)*16 + fo];
            v8s bu1 = *(const v8s*)&UT[(32+m)*XTS + (((32+m))>>4)*16 + fo];
            accX0 = mfma32(P[kk], bx0, accX0);
            accX1 = mfma32(P[kk], bx1, accX1);
            accU0 = mfma32(P[kk], bu0, accU0);
            accU1 = mfma32(P[kk], bu1, accU1);
        }
    }

    // ---- epilogue: normalize, O.W1^T, relu, fp32 stores ----
    __syncthreads();                           // all PV reads done
    rs += __shfl_xor(rs, 32);                  // full row sum (>= 1)
    float inv = 1.0f / rs;

    unsigned short* Ox = SH;                   // [128][XTS]
    unsigned short* Ou = SH + 128*XTS;         // [128][XTS]
    unsigned short* Wt = SH + 256*XTS;         // [64][XTS]

    #pragma unroll
    for (int r = 0; r < 16; ++r) {
        int il = (r & 3) + 8*(r >> 2) + 4*hi;
        float iv = __shfl(inv, il);
        int row = w*32 + il;
        Ox[row*XTS + m]      = f2bf_r(accX0[r] * iv);
        Ox[row*XTS + 32 + m] = f2bf_r(accX1[r] * iv);
        Ou[row*XTS + m]      = f2bf_r(accU0[r] * iv);
        Ou[row*XTS + 32 + m] = f2bf_r(accU1[r] * iv);
    }
    // W1 tile (hi only) -> Wt
    {
        const int sr = tid >> 2, fc = (tid & 3) * 16;
        const float* wb = W1 + sr*FF + fc;
        float tf[8]; U16x8 H;
        #pragma unroll
        for (int h = 0; h < 2; ++h) {
            *(float4*)&tf[0] = ((const float4*)wb)[2*h];
            *(float4*)&tf[4] = ((const float4*)wb)[2*h+1];
            cvt8h(tf, H);
            *(uint4*)&Wt[sr*XTS + fc + h*8] = H.v;
        }
    }
    __syncthreads();

    v8s ao[4], aq[4];
    #pragma unroll
    for (int kk = 0; kk < 4; ++kk) {
        const int fo = kk*16 + hi*8;
        ao[kk] = *(const v8s*)&Ox[(w*32 + m)*XTS + fo];
        aq[kk] = *(const v8s*)&Ou[(w*32 + m)*XTS + fo];
    }
    #pragma unroll
    for (int ot = 0; ot < 2; ++ot) {
        v16f ax = (v16f)(0.0f), au = (v16f)(0.0f);
        #pragma unroll
        for (int kk = 0; kk < 4; ++kk) {
            const int fo = kk*16 + hi*8;
            v8s bw = *(const v8s*)&Wt[(ot*32 + m)*XTS + fo];
            ax = mfma32(ao[kk], bw, ax);
            au = mfma32(aq[kk], bw, au);
        }
        #pragma unroll
        for (int r = 0; r < 16; ++r) {
            int il = (r & 3) + 8*(r >> 2) + 4*hi;
            int i = i0 + w*32 + il;
            int o = ot*32 + m;
            size_t idx = ((size_t)((b*NN + i)*TT + t))*FF + o;
            out[idx]           = fmaxf(ax[r], 0.0f);
            out[OUT_OFF + idx] = fmaxf(au[r], 0.0f);
        }
    }
}

extern "C" void kernel_launch(void* const* d_in, const int* in_sizes, int n_in,
                              void* d_out, int out_size, void* d_ws, size_t ws_size,
                              hipStream_t stream) {
    const float* ori = (const float*)d_in[0];
    const float* unc = (const float*)d_in[1];
    const float* emb = (const float*)d_in[2];
    const float* W1  = (const float*)d_in[3];
    float* out = (float*)d_out;

    spag_kernel<<<dim3(BB*TT*4), dim3(256), 0, stream>>>(ori, unc, emb, W1, out);
}